// Round 9
// baseline (1787.968 us; speedup 1.0000x reference)
//
#include <hip/hip_runtime.h>

#define TT 60
#define EC 384

typedef __attribute__((ext_vector_type(8))) short short8v;
typedef __attribute__((ext_vector_type(16))) float f32x16;

__device__ __forceinline__ unsigned short f2bf(float f) {
  unsigned u = __float_as_uint(f);
  u += 0x7fff + ((u >> 16) & 1);
  return (unsigned short)(u >> 16);
}
__device__ __forceinline__ float bf2f(unsigned short h) {
  return __uint_as_float(((unsigned)h) << 16);
}
__device__ __forceinline__ float sigmoidf_(float x) {
  return 1.f / (1.f + __expf(-x));
}
__device__ __forceinline__ float tanhf_(float x) {
  x = fminf(fmaxf(x, -15.f), 15.f);
  float e = __expf(-2.f * x);
  return (1.f - e) / (1.f + e);
}

#define MF(a, b, c) __builtin_amdgcn_mfma_f32_32x32x16_bf16(a, b, c, 0, 0, 0)

// ---- weight packing: W~[r~][k] -> lane-linear fragment order, split hi/lo bf16.
// (verified rounds 2/3/5/6/7/8)
__global__ void pack_w(const float* __restrict__ Wih, const float* __restrict__ Whh,
                       int Kx, int ncW, unsigned short* __restrict__ dst) {
  int id = blockIdx.x * 256 + threadIdx.x;
  int total = 16 * ncW * 512;
  if (id >= total) return;
  int j = id & 7, lane = (id >> 3) & 63, c = (id >> 9) % ncW, tr = id / (512 * ncW);
  int rw = lane & 31, q = rw >> 3, dl = rw & 7;
  int R = q * 128 + tr * 8 + dl;
  int k = c * 16 + (lane >> 5) * 8 + j;
  float v = (k < Kx) ? Wih[(size_t)R * Kx + k] : Whh[(size_t)R * 128 + (k - Kx)];
  unsigned short hi = f2bf(v);
  unsigned short lo = f2bf(v - bf2f(hi));
  dst[((size_t)(tr * ncW + c) * 2 + 0) * 512 + lane * 8 + j] = hi;
  dst[((size_t)(tr * ncW + c) * 2 + 1) * 512 + lane * 8 + j] = lo;
}

__global__ void pack_bias(const float* b0i, const float* b0h, const float* b1i, const float* b1h,
                          float* __restrict__ dst) {
  int tid = blockIdx.x * 256 + threadIdx.x;
  if (tid >= 1024) return;
  int l = tid >> 9, rr = tid & 511;
  int tr = rr >> 5, rw = rr & 31, q = rw >> 3, dl = rw & 7;
  int R = q * 128 + tr * 8 + dl;
  dst[tid] = l ? (b1i[R] + b1h[R]) : (b0i[R] + b0h[R]);
}

struct NArgs {
  const unsigned short* w0f;
  const unsigned short* w1f;
  const float* x;
  const float* biasP;
  float* h1f32;
};

// Node-parallel fused 2-layer LSTM, v5.
// Block = 32 nodes x all 512 gate rows; 16 waves x 1 row-tile (tr = wave id).
// Sized to FIT a 64-VGPR allocation (rounds 6-8 proved the compiler pins 64
// and spills anything bigger): depth-2 W-queue (16 VGPR) + acc (16) + c (8).
// Double-buffered h LDS -> ONE __syncthreads per step (was 3), so the
// compiler's vmcnt-drain-at-barrier hits once per step and the cross-barrier
// weight prefetch survives. 25 slots/step is odd -> two-body unroll with
// QA/QB roles swapped keeps every W-register reference compile-time static.
__global__ __launch_bounds__(1024) void lstm_node(NArgs P) {
  __shared__ unsigned short hl0[2 * 8192];   // [buf][chunk][hi/lo][512] h0
  __shared__ unsigned short hl1[2 * 8192];   // same for h1
  __shared__ float biasL[1024];
  const int tid = threadIdx.x;
  const int lane = tid & 63;
  const int tr = tid >> 6;                   // 0..15
  const int lanelo = lane & 31, lanehi = lane >> 5;
  const int node = blockIdx.x * 32 + lanelo; // 125*32 = 4000 exact

  biasL[tid] = P.biasP[tid];
  for (int i = tid; i < 8192; i += 1024) {
    ((unsigned*)hl0)[i] = 0u;
    ((unsigned*)hl1)[i] = 0u;
  }

  const unsigned short* pw0 = P.w0f + (size_t)(tr * 9) * 1024 + lane * 8;
  const unsigned short* pw1 = P.w1f + (size_t)(tr * 16) * 1024 + lane * 8;
  const int dstoff = (tr >> 1) * 1024 + (lanelo + 32 * (tr & 1)) * 8 + 4 * lanehi;
  // buffer-0 / buffer-1 read bases and write ptrs
  const unsigned short* rb0_0 = hl0 + lane * 8;
  const unsigned short* rb0_1 = hl0 + 8192 + lane * 8;
  const unsigned short* rb1_0 = hl1 + lane * 8;
  const unsigned short* rb1_1 = hl1 + 8192 + lane * 8;
  unsigned short* wp0_0 = hl0 + dstoff;
  unsigned short* wp0_1 = hl0 + 8192 + dstoff;
  unsigned short* wp1_0 = hl1 + dstoff;
  unsigned short* wp1_1 = hl1 + 8192 + dstoff;
  const int D0 = tr * 8 + 4 * lanehi;

  float c0r[4] = {0.f, 0.f, 0.f, 0.f};
  float c1r[4] = {0.f, 0.f, 0.f, 0.f};

  short8v whA, wlA, whB, wlB;
#define LW(Q, PTR) do { wh##Q = *(const short8v*)(PTR); wl##Q = *(const short8v*)((PTR) + 512); } while (0)
#define DOS(Q, BPTR, WNEXT) do { \
    const unsigned short* _b = (BPTR); \
    short8v _bh = *(const short8v*)_b; \
    short8v _bl = *(const short8v*)(_b + 512); \
    acc = MF(wh##Q, _bh, acc); \
    acc = MF(wh##Q, _bl, acc); \
    acc = MF(wl##Q, _bh, acc); \
    LW(Q, WNEXT); \
  } while (0)

  auto epi = [&](const f32x16& acc, float (&cr)[4], unsigned short* dst, bool wf32) {
    float ho[4];
    #pragma unroll
    for (int dl = 0; dl < 4; dl++) {
      float i_ = sigmoidf_(acc[dl]);
      float f_ = sigmoidf_(acc[4 + dl]);
      float g_ = tanhf_(acc[8 + dl]);
      float o_ = sigmoidf_(acc[12 + dl]);
      float cn = f_ * cr[dl] + i_ * g_;
      cr[dl] = cn;
      ho[dl] = o_ * tanhf_(cn);
    }
    if (wf32)
      *(float4*)(P.h1f32 + (size_t)node * 128 + D0) = make_float4(ho[0], ho[1], ho[2], ho[3]);
    ushort4 hs, ls;
    hs.x = f2bf(ho[0]); ls.x = f2bf(ho[0] - bf2f(hs.x));
    hs.y = f2bf(ho[1]); ls.y = f2bf(ho[1] - bf2f(hs.y));
    hs.z = f2bf(ho[2]); ls.z = f2bf(ho[2] - bf2f(hs.z));
    hs.w = f2bf(ho[3]); ls.w = f2bf(ho[3] - bf2f(hs.w));
    *(ushort4*)dst = hs;
    *(ushort4*)(dst + 512) = ls;
  };

// One LSTM step. QA holds W for even global slots, QB for odd.
// R0P: h0(t-1) read base; D0: h0(t) write; R0C: h0(t) read base (after barrier);
// R1P: h1(t-1) read base; D1: h1(t) write.
#define STEP(QA, QB, TVAL, R0P, D0, R0C, R1P, D1, WLAST) do { \
    f32x16 acc; \
    _Pragma("unroll") \
    for (int r = 0; r < 16; r++) \
      acc[r] = biasL[tr * 32 + (r & 3) + 8 * (r >> 2) + 4 * lanehi]; \
    { /* slot 0: x */ \
      const float* xp = P.x + ((size_t)node * TT + (TVAL)) * 16 + lanehi * 8; \
      float4 f0v = *(const float4*)xp, f1v = *(const float4*)(xp + 4); \
      float fv[8] = {f0v.x, f0v.y, f0v.z, f0v.w, f1v.x, f1v.y, f1v.z, f1v.w}; \
      union { short8v v; unsigned short u[8]; } XH, XL; \
      _Pragma("unroll") \
      for (int e = 0; e < 8; e++) { \
        unsigned short h = f2bf(fv[e]); \
        XH.u[e] = h; XL.u[e] = f2bf(fv[e] - bf2f(h)); \
      } \
      acc = MF(wh##QA, XH.v, acc); \
      acc = MF(wh##QA, XL.v, acc); \
      acc = MF(wl##QA, XH.v, acc); \
      LW(QA, pw0 + 2 * 1024); \
    } \
    DOS(QB, (R0P) + 0 * 1024, pw0 + 3 * 1024); \
    DOS(QA, (R0P) + 1 * 1024, pw0 + 4 * 1024); \
    DOS(QB, (R0P) + 2 * 1024, pw0 + 5 * 1024); \
    DOS(QA, (R0P) + 3 * 1024, pw0 + 6 * 1024); \
    DOS(QB, (R0P) + 4 * 1024, pw0 + 7 * 1024); \
    DOS(QA, (R0P) + 5 * 1024, pw0 + 8 * 1024); \
    DOS(QB, (R0P) + 6 * 1024, pw1 + 0 * 1024); \
    DOS(QA, (R0P) + 7 * 1024, pw1 + 1 * 1024); \
    epi(acc, c0r, D0, false); \
    __syncthreads(); \
    _Pragma("unroll") \
    for (int r = 0; r < 16; r++) \
      acc[r] = biasL[512 + tr * 32 + (r & 3) + 8 * (r >> 2) + 4 * lanehi]; \
    DOS(QB, (R0C) + 0 * 1024, pw1 + 2 * 1024); \
    DOS(QA, (R0C) + 1 * 1024, pw1 + 3 * 1024); \
    DOS(QB, (R0C) + 2 * 1024, pw1 + 4 * 1024); \
    DOS(QA, (R0C) + 3 * 1024, pw1 + 5 * 1024); \
    DOS(QB, (R0C) + 4 * 1024, pw1 + 6 * 1024); \
    DOS(QA, (R0C) + 5 * 1024, pw1 + 7 * 1024); \
    DOS(QB, (R0C) + 6 * 1024, pw1 + 8 * 1024); \
    DOS(QA, (R0C) + 7 * 1024, pw1 + 9 * 1024); \
    DOS(QB, (R1P) + 0 * 1024, pw1 + 10 * 1024); \
    DOS(QA, (R1P) + 1 * 1024, pw1 + 11 * 1024); \
    DOS(QB, (R1P) + 2 * 1024, pw1 + 12 * 1024); \
    DOS(QA, (R1P) + 3 * 1024, pw1 + 13 * 1024); \
    DOS(QB, (R1P) + 4 * 1024, pw1 + 14 * 1024); \
    DOS(QA, (R1P) + 5 * 1024, pw1 + 15 * 1024); \
    DOS(QB, (R1P) + 6 * 1024, pw0 + 0 * 1024); \
    DOS(QA, (R1P) + 7 * 1024, pw0 + 1 * 1024); \
    epi(acc, c1r, D1, WLAST); \
  } while (0)

  // prologue: QA = W0 chunk0, QB = W0 chunk1
  LW(A, pw0);
  LW(B, pw0 + 1024);
  __syncthreads();   // biasL + zeroed hl ready

  for (int t2 = 0; t2 < TT; t2 += 2) {
    // even t: reads buf1 (h(t-1)), writes buf0
    STEP(A, B, t2, rb0_1, wp0_0, rb0_0, rb1_1, wp1_0, false);
    // odd t: reads buf0, writes buf1 (QA/QB roles swapped: 25 slots is odd)
    STEP(B, A, t2 + 1, rb0_0, wp0_1, rb0_1, rb1_0, wp1_1, (t2 + 1) == TT - 1);
  }
#undef STEP
#undef DOS
#undef LW
}

// ---------------- attention ----------------
__global__ void attn_prep(const float* __restrict__ Wt, const float* __restrict__ bt,
                          const float* __restrict__ a, float* __restrict__ uv) {
  int k = threadIdx.x;
  float us = 0.f, ud = 0.f;
  for (int j = 0; j < 128; j++) {
    float w = Wt[j * 128 + k];
    us += a[j] * w;
    ud += a[128 + j] * w;
  }
  uv[k] = us; uv[128 + k] = ud;
  __shared__ float red[128];
  red[k] = bt[k] * a[k];
  __syncthreads();
  for (int st = 64; st; st >>= 1) { if (k < st) red[k] += red[k + st]; __syncthreads(); }
  if (k == 0) uv[256] = red[0];
  __syncthreads();
  red[k] = bt[k] * a[128 + k];
  __syncthreads();
  for (int st = 64; st; st >>= 1) { if (k < st) red[k] += red[k + st]; __syncthreads(); }
  if (k == 0) uv[257] = red[0];
}

__global__ void attn_scores(const float* __restrict__ hid, const float* __restrict__ uv,
                            float* __restrict__ ssrc, float* __restrict__ sdst, int N) {
  int wave = threadIdx.x >> 6, lane = threadIdx.x & 63;
  int i = blockIdx.x * 4 + wave;
  if (i >= N) return;
  float h0 = hid[(long)i * 128 + lane], h1 = hid[(long)i * 128 + 64 + lane];
  float us = h0 * uv[lane] + h1 * uv[64 + lane];
  float ud = h0 * uv[128 + lane] + h1 * uv[192 + lane];
  for (int off = 32; off; off >>= 1) { us += __shfl_down(us, off); ud += __shfl_down(ud, off); }
  if (lane == 0) { ssrc[i] = us + uv[256]; sdst[i] = ud + uv[257]; }
}

__global__ void colsum_part(const float* __restrict__ hid, float* __restrict__ part, int N) {
  int d = threadIdx.x, b = blockIdx.x;
  int per = (N + 31) / 32;
  int n0 = b * per, n1 = min(N, n0 + per);
  float s = 0.f;
  for (int n = n0; n < n1; n++) s += hid[(long)n * 128 + d];
  part[b * 128 + d] = s;
}
__global__ void colsum_fold(const float* __restrict__ part, float* __restrict__ csum) {
  int d = threadIdx.x;
  float s = 0.f;
  for (int b = 0; b < 32; b++) s += part[b * 128 + d];
  csum[d] = s;
}

// One-time adjacency scan -> per-row edge lists (adj identical both rounds).
__global__ __launch_bounds__(256) void build_csr(const float* __restrict__ adj, int* __restrict__ deg,
                                                 int* __restrict__ eidx, int N) {
  const int i = blockIdx.x, tid = threadIdx.x;
  __shared__ int cnt;
  if (tid == 0) cnt = 0;
  __syncthreads();
  const float4* arow = (const float4*)(adj + (size_t)i * N);
  for (int v = tid; v < N / 4; v += 256) {
    float4 a = arow[v];
    int j = 4 * v;
    if (a.x != 0.f) { int k = atomicAdd(&cnt, 1); if (k < EC) eidx[(size_t)i * EC + k] = j; }
    if (a.y != 0.f) { int k = atomicAdd(&cnt, 1); if (k < EC) eidx[(size_t)i * EC + k] = j + 1; }
    if (a.z != 0.f) { int k = atomicAdd(&cnt, 1); if (k < EC) eidx[(size_t)i * EC + k] = j + 2; }
    if (a.w != 0.f) { int k = atomicAdd(&cnt, 1); if (k < EC) eidx[(size_t)i * EC + k] = j + 3; }
  }
  __syncthreads();
  if (tid == 0) deg[i] = cnt;
}

// Sparse masked-softmax + gather over precomputed edges.
__global__ __launch_bounds__(256) void attn_apply(const int* __restrict__ deg, const int* __restrict__ eidx,
    const float* __restrict__ adj, const float* __restrict__ ssrc, const float* __restrict__ sdst,
    const float* __restrict__ hid, const float* __restrict__ csum, float* __restrict__ hout, int N) {
  const int i = blockIdx.x, tid = threadIdx.x;
  __shared__ float sw[EC];
  __shared__ int sidx[EC];
  __shared__ float red[256];
  const int cnt = deg[i];
  const float sd = sdst[i];
  const bool fits = (cnt <= EC);
  float m = 0.f;
  if (fits) {
    for (int k = tid; k < cnt; k += 256) {
      int j = eidx[(size_t)i * EC + k];
      float s = sd + ssrc[j];
      s = s > 0.f ? s : 0.01f * s;
      sidx[k] = j; sw[k] = s;
      m = fmaxf(m, s);
    }
  } else {
    const float* arow = adj + (size_t)i * N;
    for (int j = tid; j < N; j += 256)
      if (arow[j] != 0.f) { float s = sd + ssrc[j]; s = s > 0.f ? s : 0.01f * s; m = fmaxf(m, s); }
  }
  red[tid] = m; __syncthreads();
  for (int st = 128; st; st >>= 1) { if (tid < st) red[tid] = fmaxf(red[tid], red[tid + st]); __syncthreads(); }
  m = red[0];
  const float e0 = __expf(-m);
  float dc = 0.f;
  if (fits) {
    for (int k = tid; k < cnt; k += 256) { float w2 = __expf(sw[k] - m) - e0; sw[k] = w2; dc += w2; }
  } else {
    const float* arow = adj + (size_t)i * N;
    for (int j = tid; j < N; j += 256)
      if (arow[j] != 0.f) { float s = sd + ssrc[j]; s = s > 0.f ? s : 0.01f * s; dc += __expf(s - m) - e0; }
  }
  __syncthreads();
  red[tid] = dc; __syncthreads();
  for (int st = 128; st; st >>= 1) { if (tid < st) red[tid] += red[tid + st]; __syncthreads(); }
  const float inv = 1.f / ((float)N * e0 + red[0]);
  const int d = tid & 127, g = tid >> 7;
  float acc = 0.f;
  if (fits) {
    #pragma unroll 4
    for (int k = g; k < cnt; k += 2)
      acc += sw[k] * hid[(size_t)sidx[k] * 128 + d];
  } else {
    const float* arow = adj + (size_t)i * N;
    for (int j = g; j < N; j += 2) {
      if (arow[j] != 0.f) {
        float s = sd + ssrc[j]; s = s > 0.f ? s : 0.01f * s;
        acc += (__expf(s - m) - e0) * hid[(size_t)j * 128 + d];
      }
    }
  }
  __syncthreads();
  red[tid] = acc; __syncthreads();
  if (g == 0) {
    float tot = e0 * csum[d] + red[tid] + red[128 + tid];
    hout[(size_t)i * 128 + d] = tot * inv + hid[(size_t)i * 128 + d];
  }
}

// out[n] = Wout . leaky(hid[n] @ Wfc^T + bfc) + bout
__global__ __launch_bounds__(256) void head_kernel(const float* __restrict__ hid, const float* __restrict__ Wfc,
                            const float* __restrict__ bfc, const float* __restrict__ Wout,
                            const float* __restrict__ bout, float* __restrict__ out, int N) {
  __shared__ float wT[64 * 128];   // [k][j]
  __shared__ float hL[32 * 64];    // [r][k]
  const int tid = threadIdx.x;
  const int row0 = blockIdx.x * 32;
  const int js = tid & 31, r0 = (tid >> 5) * 4;

  float fc[4][4];
  #pragma unroll
  for (int ri = 0; ri < 4; ri++)
    #pragma unroll
    for (int ji = 0; ji < 4; ji++) fc[ri][ji] = 0.f;

  for (int half = 0; half < 2; half++) {
    const int k0 = half * 64;
    __syncthreads();
    {
      int jj = tid & 127, kg = (tid >> 7) * 32;
      for (int kk = 0; kk < 32; kk++)
        wT[(kg + kk) * 128 + jj] = Wfc[(size_t)jj * 128 + k0 + kg + kk];
      int rr = tid >> 3, ks = (tid & 7) * 8;
      float4 a = *(const float4*)(hid + (size_t)(row0 + rr) * 128 + k0 + ks);
      float4 b = *(const float4*)(hid + (size_t)(row0 + rr) * 128 + k0 + ks + 4);
      *(float4*)(hL + rr * 64 + ks) = a;
      *(float4*)(hL + rr * 64 + ks + 4) = b;
    }
    __syncthreads();
    #pragma unroll 4
    for (int k = 0; k < 64; k++) {
      float h0 = hL[(r0 + 0) * 64 + k];
      float h1 = hL[(r0 + 1) * 64 + k];
      float h2 = hL[(r0 + 2) * 64 + k];
      float h3 = hL[(r0 + 3) * 64 + k];
      #pragma unroll
      for (int ji = 0; ji < 4; ji++) {
        float wv2 = wT[k * 128 + js + 32 * ji];
        fc[0][ji] += h0 * wv2;
        fc[1][ji] += h1 * wv2;
        fc[2][ji] += h2 * wv2;
        fc[3][ji] += h3 * wv2;
      }
    }
  }

  float wo[4], bj[4];
  #pragma unroll
  for (int ji = 0; ji < 4; ji++) { wo[ji] = Wout[js + 32 * ji]; bj[ji] = bfc[js + 32 * ji]; }
  float bo = bout[0];
  #pragma unroll
  for (int ri = 0; ri < 4; ri++) {
    float v = 0.f;
    #pragma unroll
    for (int ji = 0; ji < 4; ji++) {
      float g = fc[ri][ji] + bj[ji];
      g = g > 0.f ? g : 0.01f * g;
      v += wo[ji] * g;
    }
    v += __shfl_down(v, 16);
    v += __shfl_down(v, 8);
    v += __shfl_down(v, 4);
    v += __shfl_down(v, 2);
    v += __shfl_down(v, 1);
    if (js == 0) out[row0 + r0 + ri] = v + bo;
  }
}

extern "C" void kernel_launch(void* const* d_in, const int* in_sizes, int n_in,
                              void* d_out, int out_size, void* d_ws, size_t ws_size,
                              hipStream_t stream) {
  const float* x    = (const float*)d_in[0];
  const float* adj  = (const float*)d_in[1];
  const float* Wih0 = (const float*)d_in[2];
  const float* Whh0 = (const float*)d_in[3];
  const float* bih0 = (const float*)d_in[4];
  const float* bhh0 = (const float*)d_in[5];
  const float* Wih1 = (const float*)d_in[6];
  const float* Whh1 = (const float*)d_in[7];
  const float* bih1 = (const float*)d_in[8];
  const float* bhh1 = (const float*)d_in[9];
  const float* Wtr  = (const float*)d_in[10];
  const float* btr  = (const float*)d_in[11];
  const float* avec = (const float*)d_in[12];
  const float* Wfc  = (const float*)d_in[13];
  const float* bfc  = (const float*)d_in[14];
  const float* Wout = (const float*)d_in[15];
  const float* bout = (const float*)d_in[16];
  float* out = (float*)d_out;

  const int N = 4000;
  char* base = (char*)d_ws;
  size_t off = 0;
  auto alloc = [&](size_t bytes) { char* p = base + off; off += (bytes + 255) & ~(size_t)255; return p; };

  float* h1a  = (float*)alloc((size_t)N * 128 * 4);
  float* h1b  = (float*)alloc((size_t)N * 128 * 4);
  unsigned short* w0f  = (unsigned short*)alloc((size_t)16 * 9 * 2 * 512 * 2);
  unsigned short* w1f  = (unsigned short*)alloc((size_t)16 * 16 * 2 * 512 * 2);
  float* biasP = (float*)alloc(1024 * 4);
  float* ssrc = (float*)alloc(N * 4);
  float* sdst = (float*)alloc(N * 4);
  float* uv   = (float*)alloc(272 * 4);
  float* part = (float*)alloc(4096 * 4);
  float* csum = (float*)alloc(128 * 4);
  int* deg    = (int*)alloc((size_t)N * 4);
  int* eidx   = (int*)alloc((size_t)N * EC * 4);

  hipLaunchKernelGGL(pack_w, dim3(288), dim3(256), 0, stream, Wih0, Whh0, 16, 9, w0f);
  hipLaunchKernelGGL(pack_w, dim3(512), dim3(256), 0, stream, Wih1, Whh1, 128, 16, w1f);
  hipLaunchKernelGGL(pack_bias, dim3(4), dim3(256), 0, stream, bih0, bhh0, bih1, bhh1, biasP);
  hipLaunchKernelGGL(build_csr, dim3(N), dim3(256), 0, stream, adj, deg, eidx, N);

  NArgs na;
  na.w0f = w0f; na.w1f = w1f; na.x = x; na.biasP = biasP; na.h1f32 = h1a;
  hipLaunchKernelGGL(lstm_node, dim3(125), dim3(1024), 0, stream, na);

  hipLaunchKernelGGL(attn_prep, dim3(1), dim3(128), 0, stream, Wtr, btr, avec, uv);
  for (int r = 0; r < 2; r++) {
    const float* hid = r ? h1b : h1a;
    float* hnew = r ? h1a : h1b;
    hipLaunchKernelGGL(attn_scores, dim3(1000), dim3(256), 0, stream, hid, uv, ssrc, sdst, N);
    hipLaunchKernelGGL(colsum_part, dim3(32), dim3(128), 0, stream, hid, part, N);
    hipLaunchKernelGGL(colsum_fold, dim3(1), dim3(128), 0, stream, part, csum);
    hipLaunchKernelGGL(attn_apply, dim3(N), dim3(256), 0, stream, deg, eidx, adj, ssrc, sdst, hid, csum, hnew, N);
  }
  hipLaunchKernelGGL(head_kernel, dim3(125), dim3(256), 0, stream, h1a, Wfc, bfc, Wout, bout, out, N);
}

// Round 10
// 900.745 us; speedup vs baseline: 1.9850x; 1.9850x over previous
//
#include <hip/hip_runtime.h>

#define TT 60
#define EC 384

typedef __attribute__((ext_vector_type(8))) short short8v;
typedef __attribute__((ext_vector_type(16))) float f32x16;

__device__ __forceinline__ unsigned short f2bf(float f) {
  unsigned u = __float_as_uint(f);
  u += 0x7fff + ((u >> 16) & 1);
  return (unsigned short)(u >> 16);
}
__device__ __forceinline__ float bf2f(unsigned short h) {
  return __uint_as_float(((unsigned)h) << 16);
}
__device__ __forceinline__ float sigmoidf_(float x) {
  return 1.f / (1.f + __expf(-x));
}
__device__ __forceinline__ float tanhf_(float x) {
  x = fminf(fmaxf(x, -15.f), 15.f);
  float e = __expf(-2.f * x);
  return (1.f - e) / (1.f + e);
}

#define MF(a, b, c) __builtin_amdgcn_mfma_f32_32x32x16_bf16(a, b, c, 0, 0, 0)

// ---- weight packing: W~[r~][k] -> lane-linear fragment order, split hi/lo bf16.
__global__ void pack_w(const float* __restrict__ Wih, const float* __restrict__ Whh,
                       int Kx, int ncW, unsigned short* __restrict__ dst) {
  int id = blockIdx.x * 256 + threadIdx.x;
  int total = 16 * ncW * 512;
  if (id >= total) return;
  int j = id & 7, lane = (id >> 3) & 63, c = (id >> 9) % ncW, tr = id / (512 * ncW);
  int rw = lane & 31, q = rw >> 3, dl = rw & 7;
  int R = q * 128 + tr * 8 + dl;
  int k = c * 16 + (lane >> 5) * 8 + j;
  float v = (k < Kx) ? Wih[(size_t)R * Kx + k] : Whh[(size_t)R * 128 + (k - Kx)];
  unsigned short hi = f2bf(v);
  unsigned short lo = f2bf(v - bf2f(hi));
  dst[((size_t)(tr * ncW + c) * 2 + 0) * 512 + lane * 8 + j] = hi;
  dst[((size_t)(tr * ncW + c) * 2 + 1) * 512 + lane * 8 + j] = lo;
}

__global__ void pack_bias(const float* b0i, const float* b0h, const float* b1i, const float* b1h,
                          float* __restrict__ dst) {
  int tid = blockIdx.x * 256 + threadIdx.x;
  if (tid >= 1024) return;
  int l = tid >> 9, rr = tid & 511;
  int tr = rr >> 5, rw = rr & 31, q = rw >> 3, dl = rw & 7;
  int R = q * 128 + tr * 8 + dl;
  dst[tid] = l ? (b1i[R] + b1h[R]) : (b0i[R] + b0h[R]);
}

struct SArgs {
  const unsigned short* W; int ncW;
  const float* xf32;              // layer0: fp32 x_t (stride 960); chunk 0
  const unsigned short* Bx; int bxc;  // layer1: h0split (8 chunks)
  const unsigned short* Bh;       // own h split (null at t=0)
  const float* cin; float* cout;
  unsigned short* hout; float* hf32;
  const float* bias;
  int active;
};

struct Ch {
  short8v wh, wl, b0h, b0l, b1h, b1l;
};

// Round-3 kernel verbatim (measured ~13 us/step incl. launch overhead):
// gates^T = W~ . [x|h]; wave tile = 32 gate-rows x 64 nodes; no LDS/barriers;
// 3-deep register prefetch at 256 threads (allocator grants ~128+ VGPRs here,
// unlike 1024-thread blocks which pin 64 and spill - rounds 6-9).
__global__ __launch_bounds__(256) void lstm_mfma(SArgs A0, SArgs A1) {
  SArgs La = blockIdx.z ? A1 : A0;
  if (!La.active) return;
  const int tid = threadIdx.x;
  const int lane = tid & 63, w = tid >> 6;
  const int tr = blockIdx.y * 4 + w;
  const int nt0 = blockIdx.x * 2;
  const bool has1 = (nt0 + 1) < 125;
  const int nt1 = has1 ? nt0 + 1 : nt0;
  const int lanelo = lane & 31, lanehi = lane >> 5;
  const int x0 = La.xf32 ? 1 : 0;
  const int nc = x0 + La.bxc + (La.Bh ? 8 : 0);

  f32x16 acc0, acc1;
  #pragma unroll
  for (int r = 0; r < 16; r++) {
    float b = La.bias[tr * 32 + (r & 3) + 8 * (r >> 2) + 4 * lanehi];
    acc0[r] = b; acc1[r] = b;
  }

  auto loadCh = [&](Ch& P, int c) {
    {
      const unsigned short* p = La.W + ((size_t)(tr * La.ncW + c) * 2) * 512 + lane * 8;
      P.wh = *(const short8v*)p;
      P.wl = *(const short8v*)(p + 512);
    }
    if (x0 && c == 0) {
      const float* xp0 = La.xf32 + (size_t)(nt0 * 32 + lanelo) * 960 + lanehi * 8;
      const float* xp1 = La.xf32 + (size_t)(nt1 * 32 + lanelo) * 960 + lanehi * 8;
      float4 a0 = *(const float4*)xp0, a1 = *(const float4*)(xp0 + 4);
      float4 b0 = *(const float4*)xp1, b1 = *(const float4*)(xp1 + 4);
      float f0[8] = {a0.x, a0.y, a0.z, a0.w, a1.x, a1.y, a1.z, a1.w};
      float f1[8] = {b0.x, b0.y, b0.z, b0.w, b1.x, b1.y, b1.z, b1.w};
      union { short8v v; unsigned short s[8]; } H0, L0, H1, L1;
      #pragma unroll
      for (int e = 0; e < 8; e++) {
        unsigned short h0 = f2bf(f0[e]); H0.s[e] = h0; L0.s[e] = f2bf(f0[e] - bf2f(h0));
        unsigned short h1 = f2bf(f1[e]); H1.s[e] = h1; L1.s[e] = f2bf(f1[e] - bf2f(h1));
      }
      P.b0h = H0.v; P.b0l = L0.v; P.b1h = H1.v; P.b1l = L1.v;
    } else {
      int cc = c - x0;
      const unsigned short* base; int cl;
      if (cc < La.bxc) { base = La.Bx; cl = cc; }
      else             { base = La.Bh; cl = cc - La.bxc; }
      const int stride = (cc < La.bxc) ? La.bxc : 8;
      const unsigned short* p0 = base + ((size_t)(nt0 * stride + cl) * 2) * 512 + lane * 8;
      const unsigned short* p1 = base + ((size_t)(nt1 * stride + cl) * 2) * 512 + lane * 8;
      P.b0h = *(const short8v*)p0;
      P.b0l = *(const short8v*)(p0 + 512);
      P.b1h = *(const short8v*)p1;
      P.b1l = *(const short8v*)(p1 + 512);
    }
  };

  auto compCh = [&](const Ch& P) {
    acc0 = MF(P.wh, P.b0h, acc0);
    acc1 = MF(P.wh, P.b1h, acc1);
    acc0 = MF(P.wh, P.b0l, acc0);
    acc1 = MF(P.wh, P.b1l, acc1);
    acc0 = MF(P.wl, P.b0h, acc0);
    acc1 = MF(P.wl, P.b1h, acc1);
  };

  Ch p0, p1, p2;
  loadCh(p0, 0);
  if (nc > 1) loadCh(p1, 1);
  if (nc > 2) loadCh(p2, 2);
  for (int c = 0; c < nc; c += 3) {
    compCh(p0);
    if (c + 3 < nc) loadCh(p0, c + 3);
    if (c + 1 < nc) {
      compCh(p1);
      if (c + 4 < nc) loadCh(p1, c + 4);
    }
    if (c + 2 < nc) {
      compCh(p2);
      if (c + 5 < nc) loadCh(p2, c + 5);
    }
  }

  auto epi = [&](int nt, const f32x16& acc) {
    int node = nt * 32 + lanelo;
    int D0 = tr * 8 + 4 * lanehi;
    float colda[4] = {0.f, 0.f, 0.f, 0.f};
    if (La.cin) {
      float4 c4 = *(const float4*)(La.cin + (size_t)node * 128 + D0);
      colda[0] = c4.x; colda[1] = c4.y; colda[2] = c4.z; colda[3] = c4.w;
    }
    float co[4], ho[4];
    #pragma unroll
    for (int dl = 0; dl < 4; dl++) {
      float gi = acc[dl], gf = acc[4 + dl], gg = acc[8 + dl], go = acc[12 + dl];
      float i_ = sigmoidf_(gi), f_ = sigmoidf_(gf);
      float g_ = tanhf_(gg),    o_ = sigmoidf_(go);
      float cn = f_ * colda[dl] + i_ * g_;
      co[dl] = cn;
      ho[dl] = o_ * tanhf_(cn);
    }
    *(float4*)(La.cout + (size_t)node * 128 + D0) = make_float4(co[0], co[1], co[2], co[3]);
    if (La.hf32)
      *(float4*)(La.hf32 + (size_t)node * 128 + D0) = make_float4(ho[0], ho[1], ho[2], ho[3]);
    size_t hb = ((size_t)(nt * 8 + (tr >> 1)) * 2) * 512 + (lanelo + 32 * (tr & 1)) * 8 + 4 * lanehi;
    unsigned short hs[4], ls[4];
    #pragma unroll
    for (int dl = 0; dl < 4; dl++) {
      unsigned short h = f2bf(ho[dl]);
      hs[dl] = h; ls[dl] = f2bf(ho[dl] - bf2f(h));
    }
    *(ushort4*)(La.hout + hb)       = make_ushort4(hs[0], hs[1], hs[2], hs[3]);
    *(ushort4*)(La.hout + 512 + hb) = make_ushort4(ls[0], ls[1], ls[2], ls[3]);
  };
  epi(nt0, acc0);
  if (has1) epi(nt1, acc1);
}

// ---------------- attention ----------------
__global__ void attn_prep(const float* __restrict__ Wt, const float* __restrict__ bt,
                          const float* __restrict__ a, float* __restrict__ uv) {
  int k = threadIdx.x;
  float us = 0.f, ud = 0.f;
  for (int j = 0; j < 128; j++) {
    float w = Wt[j * 128 + k];
    us += a[j] * w;
    ud += a[128 + j] * w;
  }
  uv[k] = us; uv[128 + k] = ud;
  __shared__ float red[128];
  red[k] = bt[k] * a[k];
  __syncthreads();
  for (int st = 64; st; st >>= 1) { if (k < st) red[k] += red[k + st]; __syncthreads(); }
  if (k == 0) uv[256] = red[0];
  __syncthreads();
  red[k] = bt[k] * a[128 + k];
  __syncthreads();
  for (int st = 64; st; st >>= 1) { if (k < st) red[k] += red[k + st]; __syncthreads(); }
  if (k == 0) uv[257] = red[0];
}

__global__ void attn_scores(const float* __restrict__ hid, const float* __restrict__ uv,
                            float* __restrict__ ssrc, float* __restrict__ sdst, int N) {
  int wave = threadIdx.x >> 6, lane = threadIdx.x & 63;
  int i = blockIdx.x * 4 + wave;
  if (i >= N) return;
  float h0 = hid[(long)i * 128 + lane], h1 = hid[(long)i * 128 + 64 + lane];
  float us = h0 * uv[lane] + h1 * uv[64 + lane];
  float ud = h0 * uv[128 + lane] + h1 * uv[192 + lane];
  for (int off = 32; off; off >>= 1) { us += __shfl_down(us, off); ud += __shfl_down(ud, off); }
  if (lane == 0) { ssrc[i] = us + uv[256]; sdst[i] = ud + uv[257]; }
}

__global__ void colsum_part(const float* __restrict__ hid, float* __restrict__ part, int N) {
  int d = threadIdx.x, b = blockIdx.x;
  int per = (N + 31) / 32;
  int n0 = b * per, n1 = min(N, n0 + per);
  float s = 0.f;
  for (int n = n0; n < n1; n++) s += hid[(long)n * 128 + d];
  part[b * 128 + d] = s;
}
__global__ void colsum_fold(const float* __restrict__ part, float* __restrict__ csum) {
  int d = threadIdx.x;
  float s = 0.f;
  for (int b = 0; b < 32; b++) s += part[b * 128 + d];
  csum[d] = s;
}

// One-time adjacency scan -> per-row edge lists (adj identical both rounds).
__global__ __launch_bounds__(256) void build_csr(const float* __restrict__ adj, int* __restrict__ deg,
                                                 int* __restrict__ eidx, int N) {
  const int i = blockIdx.x, tid = threadIdx.x;
  __shared__ int cnt;
  if (tid == 0) cnt = 0;
  __syncthreads();
  const float4* arow = (const float4*)(adj + (size_t)i * N);
  for (int v = tid; v < N / 4; v += 256) {
    float4 a = arow[v];
    int j = 4 * v;
    if (a.x != 0.f) { int k = atomicAdd(&cnt, 1); if (k < EC) eidx[(size_t)i * EC + k] = j; }
    if (a.y != 0.f) { int k = atomicAdd(&cnt, 1); if (k < EC) eidx[(size_t)i * EC + k] = j + 1; }
    if (a.z != 0.f) { int k = atomicAdd(&cnt, 1); if (k < EC) eidx[(size_t)i * EC + k] = j + 2; }
    if (a.w != 0.f) { int k = atomicAdd(&cnt, 1); if (k < EC) eidx[(size_t)i * EC + k] = j + 3; }
  }
  __syncthreads();
  if (tid == 0) deg[i] = cnt;
}

// Sparse masked-softmax + gather over precomputed edges.
__global__ __launch_bounds__(256) void attn_apply(const int* __restrict__ deg, const int* __restrict__ eidx,
    const float* __restrict__ adj, const float* __restrict__ ssrc, const float* __restrict__ sdst,
    const float* __restrict__ hid, const float* __restrict__ csum, float* __restrict__ hout, int N) {
  const int i = blockIdx.x, tid = threadIdx.x;
  __shared__ float sw[EC];
  __shared__ int sidx[EC];
  __shared__ float red[256];
  const int cnt = deg[i];
  const float sd = sdst[i];
  const bool fits = (cnt <= EC);
  float m = 0.f;
  if (fits) {
    for (int k = tid; k < cnt; k += 256) {
      int j = eidx[(size_t)i * EC + k];
      float s = sd + ssrc[j];
      s = s > 0.f ? s : 0.01f * s;
      sidx[k] = j; sw[k] = s;
      m = fmaxf(m, s);
    }
  } else {
    const float* arow = adj + (size_t)i * N;
    for (int j = tid; j < N; j += 256)
      if (arow[j] != 0.f) { float s = sd + ssrc[j]; s = s > 0.f ? s : 0.01f * s; m = fmaxf(m, s); }
  }
  red[tid] = m; __syncthreads();
  for (int st = 128; st; st >>= 1) { if (tid < st) red[tid] = fmaxf(red[tid], red[tid + st]); __syncthreads(); }
  m = red[0];
  const float e0 = __expf(-m);
  float dc = 0.f;
  if (fits) {
    for (int k = tid; k < cnt; k += 256) { float w2 = __expf(sw[k] - m) - e0; sw[k] = w2; dc += w2; }
  } else {
    const float* arow = adj + (size_t)i * N;
    for (int j = tid; j < N; j += 256)
      if (arow[j] != 0.f) { float s = sd + ssrc[j]; s = s > 0.f ? s : 0.01f * s; dc += __expf(s - m) - e0; }
  }
  __syncthreads();
  red[tid] = dc; __syncthreads();
  for (int st = 128; st; st >>= 1) { if (tid < st) red[tid] += red[tid + st]; __syncthreads(); }
  const float inv = 1.f / ((float)N * e0 + red[0]);
  const int d = tid & 127, g = tid >> 7;
  float acc = 0.f;
  if (fits) {
    #pragma unroll 4
    for (int k = g; k < cnt; k += 2)
      acc += sw[k] * hid[(size_t)sidx[k] * 128 + d];
  } else {
    const float* arow = adj + (size_t)i * N;
    for (int j = g; j < N; j += 2) {
      if (arow[j] != 0.f) {
        float s = sd + ssrc[j]; s = s > 0.f ? s : 0.01f * s;
        acc += (__expf(s - m) - e0) * hid[(size_t)j * 128 + d];
      }
    }
  }
  __syncthreads();
  red[tid] = acc; __syncthreads();
  if (g == 0) {
    float tot = e0 * csum[d] + red[tid] + red[128 + tid];
    hout[(size_t)i * 128 + d] = tot * inv + hid[(size_t)i * 128 + d];
  }
}

// out[n] = Wout . leaky(hid[n] @ Wfc^T + bfc) + bout
__global__ __launch_bounds__(256) void head_kernel(const float* __restrict__ hid, const float* __restrict__ Wfc,
                            const float* __restrict__ bfc, const float* __restrict__ Wout,
                            const float* __restrict__ bout, float* __restrict__ out, int N) {
  __shared__ float wT[64 * 128];   // [k][j]
  __shared__ float hL[32 * 64];    // [r][k]
  const int tid = threadIdx.x;
  const int row0 = blockIdx.x * 32;
  const int js = tid & 31, r0 = (tid >> 5) * 4;

  float fc[4][4];
  #pragma unroll
  for (int ri = 0; ri < 4; ri++)
    #pragma unroll
    for (int ji = 0; ji < 4; ji++) fc[ri][ji] = 0.f;

  for (int half = 0; half < 2; half++) {
    const int k0 = half * 64;
    __syncthreads();
    {
      int jj = tid & 127, kg = (tid >> 7) * 32;
      for (int kk = 0; kk < 32; kk++)
        wT[(kg + kk) * 128 + jj] = Wfc[(size_t)jj * 128 + k0 + kg + kk];
      int rr = tid >> 3, ks = (tid & 7) * 8;
      float4 a = *(const float4*)(hid + (size_t)(row0 + rr) * 128 + k0 + ks);
      float4 b = *(const float4*)(hid + (size_t)(row0 + rr) * 128 + k0 + ks + 4);
      *(float4*)(hL + rr * 64 + ks) = a;
      *(float4*)(hL + rr * 64 + ks + 4) = b;
    }
    __syncthreads();
    #pragma unroll 4
    for (int k = 0; k < 64; k++) {
      float h0 = hL[(r0 + 0) * 64 + k];
      float h1 = hL[(r0 + 1) * 64 + k];
      float h2 = hL[(r0 + 2) * 64 + k];
      float h3 = hL[(r0 + 3) * 64 + k];
      #pragma unroll
      for (int ji = 0; ji < 4; ji++) {
        float wv2 = wT[k * 128 + js + 32 * ji];
        fc[0][ji] += h0 * wv2;
        fc[1][ji] += h1 * wv2;
        fc[2][ji] += h2 * wv2;
        fc[3][ji] += h3 * wv2;
      }
    }
  }

  float wo[4], bj[4];
  #pragma unroll
  for (int ji = 0; ji < 4; ji++) { wo[ji] = Wout[js + 32 * ji]; bj[ji] = bfc[js + 32 * ji]; }
  float bo = bout[0];
  #pragma unroll
  for (int ri = 0; ri < 4; ri++) {
    float v = 0.f;
    #pragma unroll
    for (int ji = 0; ji < 4; ji++) {
      float g = fc[ri][ji] + bj[ji];
      g = g > 0.f ? g : 0.01f * g;
      v += wo[ji] * g;
    }
    v += __shfl_down(v, 16);
    v += __shfl_down(v, 8);
    v += __shfl_down(v, 4);
    v += __shfl_down(v, 2);
    v += __shfl_down(v, 1);
    if (js == 0) out[row0 + r0 + ri] = v + bo;
  }
}

extern "C" void kernel_launch(void* const* d_in, const int* in_sizes, int n_in,
                              void* d_out, int out_size, void* d_ws, size_t ws_size,
                              hipStream_t stream) {
  const float* x    = (const float*)d_in[0];
  const float* adj  = (const float*)d_in[1];
  const float* Wih0 = (const float*)d_in[2];
  const float* Whh0 = (const float*)d_in[3];
  const float* bih0 = (const float*)d_in[4];
  const float* bhh0 = (const float*)d_in[5];
  const float* Wih1 = (const float*)d_in[6];
  const float* Whh1 = (const float*)d_in[7];
  const float* bih1 = (const float*)d_in[8];
  const float* bhh1 = (const float*)d_in[9];
  const float* Wtr  = (const float*)d_in[10];
  const float* btr  = (const float*)d_in[11];
  const float* avec = (const float*)d_in[12];
  const float* Wfc  = (const float*)d_in[13];
  const float* bfc  = (const float*)d_in[14];
  const float* Wout = (const float*)d_in[15];
  const float* bout = (const float*)d_in[16];
  float* out = (float*)d_out;

  const int N = 4000;
  char* base = (char*)d_ws;
  size_t off = 0;
  auto alloc = [&](size_t bytes) { char* p = base + off; off += (bytes + 255) & ~(size_t)255; return p; };

  float* c0   = (float*)alloc((size_t)N * 128 * 4);
  float* c1   = (float*)alloc((size_t)N * 128 * 4);
  float* h1a  = (float*)alloc((size_t)N * 128 * 4);
  float* h1b  = (float*)alloc((size_t)N * 128 * 4);
  unsigned short* h0s0 = (unsigned short*)alloc((size_t)125 * 8 * 2 * 512 * 2);
  unsigned short* h0s1 = (unsigned short*)alloc((size_t)125 * 8 * 2 * 512 * 2);
  unsigned short* h1s0 = (unsigned short*)alloc((size_t)125 * 8 * 2 * 512 * 2);
  unsigned short* h1s1 = (unsigned short*)alloc((size_t)125 * 8 * 2 * 512 * 2);
  unsigned short* w0f  = (unsigned short*)alloc((size_t)16 * 9 * 2 * 512 * 2);
  unsigned short* w1f  = (unsigned short*)alloc((size_t)16 * 16 * 2 * 512 * 2);
  float* biasP = (float*)alloc(1024 * 4);
  float* ssrc = (float*)alloc(N * 4);
  float* sdst = (float*)alloc(N * 4);
  float* uv   = (float*)alloc(272 * 4);
  float* part = (float*)alloc(4096 * 4);
  float* csum = (float*)alloc(128 * 4);
  int* deg    = (int*)alloc((size_t)N * 4);
  int* eidx   = (int*)alloc((size_t)N * EC * 4);

  unsigned short* h0s[2] = {h0s0, h0s1};
  unsigned short* h1s[2] = {h1s0, h1s1};

  hipLaunchKernelGGL(pack_w, dim3(288), dim3(256), 0, stream, Wih0, Whh0, 16, 9, w0f);
  hipLaunchKernelGGL(pack_w, dim3(512), dim3(256), 0, stream, Wih1, Whh1, 128, 16, w1f);
  hipLaunchKernelGGL(pack_bias, dim3(4), dim3(256), 0, stream, bih0, bhh0, bih1, bhh1, biasP);
  hipLaunchKernelGGL(build_csr, dim3(N), dim3(256), 0, stream, adj, deg, eidx, N);

  dim3 grid(63, 4, 2), blk(256);
  for (int s = 0; s <= TT; s++) {
    SArgs A0 = {}, A1 = {};
    A0.active = (s < TT) ? 1 : 0;
    if (A0.active) {
      int t = s;
      A0.W = w0f; A0.ncW = 9;
      A0.xf32 = x + (size_t)t * 16;
      A0.Bx = nullptr; A0.bxc = 0;
      A0.Bh = (t == 0) ? nullptr : h0s[(t + 1) & 1];
      A0.cin = (t == 0) ? nullptr : c0; A0.cout = c0;
      A0.hout = h0s[t & 1]; A0.hf32 = nullptr;
      A0.bias = biasP;
    }
    A1.active = (s >= 1) ? 1 : 0;
    if (A1.active) {
      int t = s - 1;
      A1.W = w1f; A1.ncW = 16;
      A1.xf32 = nullptr;
      A1.Bx = h0s[t & 1]; A1.bxc = 8;
      A1.Bh = (t == 0) ? nullptr : h1s[(t + 1) & 1];
      A1.cin = (t == 0) ? nullptr : c1; A1.cout = c1;
      A1.hout = h1s[t & 1]; A1.hf32 = h1a;
      A1.bias = biasP + 512;
    }
    hipLaunchKernelGGL(lstm_mfma, grid, blk, 0, stream, A0, A1);
  }

  hipLaunchKernelGGL(attn_prep, dim3(1), dim3(128), 0, stream, Wtr, btr, avec, uv);
  for (int r = 0; r < 2; r++) {
    const float* hid = r ? h1b : h1a;
    float* hnew = r ? h1a : h1b;
    hipLaunchKernelGGL(attn_scores, dim3(1000), dim3(256), 0, stream, hid, uv, ssrc, sdst, N);
    hipLaunchKernelGGL(colsum_part, dim3(32), dim3(128), 0, stream, hid, part, N);
    hipLaunchKernelGGL(colsum_fold, dim3(1), dim3(128), 0, stream, part, csum);
    hipLaunchKernelGGL(attn_apply, dim3(N), dim3(256), 0, stream, deg, eidx, adj, ssrc, sdst, hid, csum, hnew, N);
  }
  hipLaunchKernelGGL(head_kernel, dim3(125), dim3(256), 0, stream, h1a, Wfc, bfc, Wout, bout, out, N);
}